// Round 1
// baseline (1586.398 us; speedup 1.0000x reference)
//
#include <hip/hip_runtime.h>
#include <math.h>

// Problem constants (B=4, S=8192, H=4096, E=64)
#define TOKENS 32768
#define KDIM   4096
#define NE     64
#define TPB    64              // tokens per block
#define KSPLIT 8               // waves per block, K split 8 ways
#define KPER   (KDIM / KSPLIT) // 512 per thread
#define KC     16              // k-chunk (64B of H per thread per chunk)

// block = 512 threads = 8 waves; wave w handles k-range [w*KPER, (w+1)*KPER)
// lane t (0..63) = token within block. acc[e] per thread = partial logits.
// __launch_bounds__(512,4): cap VGPR at 128 so 2 blocks/CU co-reside
// (LDS 64KiB/block * 2 = 128KiB <= 160KiB) -> 16 waves/CU, 4/SIMD.
__global__ __launch_bounds__(512, 4)
void router_fwd(const float* __restrict__ Hs, const float* __restrict__ W,
                float* __restrict__ out_logits, float* __restrict__ out_aff,
                float* __restrict__ out_idx) {
    // reduction buffer: [quarter][expert][token] -> lane stride 4B, conflict-free
    __shared__ float red[4][NE][TPB]; // 64 KiB

    const int t     = threadIdx.x & 63;   // token-in-block == lane
    const int kq    = threadIdx.x >> 6;   // wave id == k-split index (wave-uniform)
    const int token = blockIdx.x * TPB + t;

    const float* __restrict__ hrow = Hs + (size_t)token * KDIM + kq * KPER;
    const float* __restrict__ wb   = W + kq * KPER; // uniform -> scalar loads

    float acc[NE];
#pragma unroll
    for (int e = 0; e < NE; ++e) acc[e] = 0.0f;

    for (int kc = 0; kc < KPER; kc += KC) {
        float h[KC];
#pragma unroll
        for (int i = 0; i < KC; i += 4) {
            const float4 v = *reinterpret_cast<const float4*>(hrow + kc + i);
            h[i] = v.x; h[i + 1] = v.y; h[i + 2] = v.z; h[i + 3] = v.w;
        }
#pragma unroll
        for (int e = 0; e < NE; ++e) {
            const float* __restrict__ wr = wb + e * KDIM + kc; // wave-uniform address
#pragma unroll
            for (int i = 0; i < KC; ++i)
                acc[e] = fmaf(h[i], wr[i], acc[e]);
        }
    }

    // ---- tree reduction over the 8 k-splits (wave-uniform branches) ----
    if (kq >= 4) {
#pragma unroll
        for (int e = 0; e < NE; ++e) red[kq - 4][e][t] = acc[e];
    }
    __syncthreads();
    if (kq < 4) {
#pragma unroll
        for (int e = 0; e < NE; ++e) acc[e] += red[kq][e][t];
    }
    __syncthreads();
    if (kq == 2 || kq == 3) {
#pragma unroll
        for (int e = 0; e < NE; ++e) red[kq - 2][e][t] = acc[e];
    }
    __syncthreads();
    if (kq < 2) {
#pragma unroll
        for (int e = 0; e < NE; ++e) acc[e] += red[kq][e][t];
    }
    __syncthreads();
    if (kq == 1) {
#pragma unroll
        for (int e = 0; e < NE; ++e) red[0][e][t] = acc[e];
    }
    __syncthreads();

    if (kq == 0) {
#pragma unroll
        for (int e = 0; e < NE; ++e) acc[e] += red[0][e][t];

        // ---- store logits ----
        float* o0 = out_logits + (size_t)token * NE;
#pragma unroll
        for (int e = 0; e < NE; e += 4)
            *reinterpret_cast<float4*>(o0 + e) =
                make_float4(acc[e], acc[e + 1], acc[e + 2], acc[e + 3]);

        // ---- softmax (precise expf + precise div to track np) ----
        float m = acc[0];
#pragma unroll
        for (int e = 1; e < NE; ++e) m = fmaxf(m, acc[e]);
        float s = 0.0f;
#pragma unroll
        for (int e = 0; e < NE; ++e) { acc[e] = expf(acc[e] - m); s += acc[e]; }
#pragma unroll
        for (int e = 0; e < NE; ++e) acc[e] = acc[e] / s;

        float* o1 = out_aff + (size_t)token * NE;
#pragma unroll
        for (int e = 0; e < NE; e += 4)
            *reinterpret_cast<float4*>(o1 + e) =
                make_float4(acc[e], acc[e + 1], acc[e + 2], acc[e + 3]);

        // ---- top-2 (stable: ties keep lower index, matching jax.lax.top_k) ----
        float b1 = -INFINITY, b2 = -INFINITY;
        int i1 = 0, i2 = 0;
#pragma unroll
        for (int e = 0; e < NE; ++e) {
            const float v = acc[e];
            if (v > b1)      { b2 = b1; i2 = i1; b1 = v; i1 = e; }
            else if (v > b2) { b2 = v; i2 = e; }
        }
        // harness reads the whole concatenated output as fp32 -> write indices as floats
        *reinterpret_cast<float2*>(out_idx + (size_t)token * 2) =
            make_float2((float)i1, (float)i2);
    }
}

extern "C" void kernel_launch(void* const* d_in, const int* in_sizes, int n_in,
                              void* d_out, int out_size, void* d_ws, size_t ws_size,
                              hipStream_t stream) {
    const float* hs = (const float*)d_in[0];  // [4,8192,4096] fp32
    const float* w  = (const float*)d_in[1];  // [64,4096] fp32
    float* out      = (float*)d_out;
    float* o_logits = out;                                  // 2097152 fp32
    float* o_aff    = out + (size_t)TOKENS * NE;            // 2097152 fp32
    float* o_idx    = out + 2 * (size_t)TOKENS * NE;        // 65536 (indices as fp32)

    dim3 grid(TOKENS / TPB); // 512 blocks
    dim3 block(512);
    hipLaunchKernelGGL(router_fwd, grid, block, 0, stream, hs, w, o_logits, o_aff, o_idx);
}